// Round 10
// baseline (459.483 us; speedup 1.0000x reference)
//
#include <hip/hip_runtime.h>
#include <hip/hip_bf16.h>

#define NN 50000
#define NROW 50048                     // 391 * 128 padded rows
#define NE 1600000
#define ETOT (NE + NN)                 // 1,650,000 (self-loops appended)
#define BN_K 0.9999950000374997f

#define SHIFT 7
#define NPB 128
#define NB ((NN + NPB - 1) >> SHIFT)   // 391
#define CAP 5120                       // fixed bucket capacity (mean 4221, +14 sigma)
#define CHUNK 4096
#define PGRID ((ETOT + CHUNK - 1) / CHUNK)
#define CVB (NROW * 32 / 256)          // 6256 blocks for x0 conversion

typedef __bf16 bf16x8 __attribute__((ext_vector_type(8)));
typedef float f32x4 __attribute__((ext_vector_type(4)));

__device__ __forceinline__ float leaky02(float x) { return x > 0.f ? x : 0.2f * x; }

__device__ __forceinline__ unsigned short f2bf(float f) {
    unsigned int u = __float_as_uint(f);
    u += 0x7FFFu + ((u >> 16) & 1u);
    return (unsigned short)(u >> 16);
}

// ---------------- init: bucket cursors + y ----------------
__global__ void init_k(int* __restrict__ bcur_d, int* __restrict__ bcur_s,
                       float* __restrict__ y) {
    int t = threadIdx.x;                 // 512
    if (t < NB) { bcur_d[t] = t * CAP; bcur_s[t] = t * CAP; }
    y[t] = 0.f;
}

// ---- combined prep: x0->bf16 | weight transpose->bf16 | fold va = W2^T att2 ----
__global__ void cvtw_k(const float* __restrict__ x0, unsigned short* __restrict__ x0b,
                       const float* __restrict__ pW, const float* __restrict__ W1,
                       unsigned short* __restrict__ pWt, unsigned short* __restrict__ W1t,
                       const float* __restrict__ W2, const float* __restrict__ as2,
                       const float* __restrict__ ad2, float* __restrict__ va_s,
                       float* __restrict__ va_d) {
    int b = blockIdx.x;
    if (b < CVB) {
        int g = b * 256 + threadIdx.x;
        int row = g >> 5;
        float4 v = make_float4(0.f, 0.f, 0.f, 0.f);
        if (row < NN) v = *(const float4*)&x0[(long)g * 4];
        ushort4 u;
        u.x = f2bf(v.x); u.y = f2bf(v.y); u.z = f2bf(v.z); u.w = f2bf(v.w);
        *(ushort4*)&x0b[(long)g * 4] = u;
    } else if (b < CVB + 2) {
        const float* in = (b - CVB) ? W1 : pW;
        unsigned short* outp = (b - CVB) ? W1t : pWt;
        for (int i = threadIdx.x; i < 16384; i += 256) {
            int n = i & 127, k = i >> 7;
            outp[n * 128 + k] = f2bf(in[k * 128 + n]);
        }
    } else {
        int h = b - CVB - 2;             // 4 blocks
        int k = threadIdx.x;
        if (k < 128) {
            const float* wrow = W2 + (long)k * 512 + h * 128;
            float accs = 0.f, accd = 0.f;
            for (int ci = 0; ci < 128; ++ci) {
                float w = wrow[ci];
                accs += w * as2[h * 128 + ci];
                accd += w * ad2[h * 128 + ci];
            }
            va_s[h * 128 + k] = accs;
            va_d[h * 128 + k] = accd;
        }
    }
}

// ---- fused MFMA chain: x1 = relu(x0@pW+pb); h1 = x1@W1 (bf16) + att dots ----
__global__ __launch_bounds__(256) void fgemm_k(
    const unsigned short* __restrict__ x0b, const unsigned short* __restrict__ pWt,
    const unsigned short* __restrict__ W1t, const float* __restrict__ pb,
    const float* __restrict__ attS, const float* __restrict__ attD,
    unsigned short* __restrict__ h1b, float* __restrict__ aS, float* __restrict__ aD) {
    __shared__ unsigned short x1s[128][136];
    const int tid = threadIdx.x;
    const int wv = tid >> 6, l = tid & 63;
    const int lr = l & 15, lg = l >> 4;
    const int r0 = blockIdx.x * 128;
    const int wr = wv * 32;

    bf16x8 Af[2][4];
    f32x4 acc[2][8];

    #pragma unroll
    for (int rt = 0; rt < 2; ++rt)
        #pragma unroll
        for (int kt = 0; kt < 4; ++kt)
            Af[rt][kt] = *(const bf16x8*)&x0b[(long)(r0 + wr + rt * 16 + lr) * 128 + kt * 32 + lg * 8];
    #pragma unroll
    for (int rt = 0; rt < 2; ++rt)
        #pragma unroll
        for (int ct = 0; ct < 8; ++ct)
            acc[rt][ct] = (f32x4){0.f, 0.f, 0.f, 0.f};
    #pragma unroll
    for (int ct = 0; ct < 8; ++ct) {
        bf16x8 Bf[4];
        #pragma unroll
        for (int kt = 0; kt < 4; ++kt)
            Bf[kt] = *(const bf16x8*)&pWt[(ct * 16 + lr) * 128 + kt * 32 + lg * 8];
        #pragma unroll
        for (int kt = 0; kt < 4; ++kt) {
            acc[0][ct] = __builtin_amdgcn_mfma_f32_16x16x32_bf16(Af[0][kt], Bf[kt], acc[0][ct], 0, 0, 0);
            acc[1][ct] = __builtin_amdgcn_mfma_f32_16x16x32_bf16(Af[1][kt], Bf[kt], acc[1][ct], 0, 0, 0);
        }
    }
    #pragma unroll
    for (int ct = 0; ct < 8; ++ct) {
        int col = ct * 16 + lr;
        float bv = pb[col];
        #pragma unroll
        for (int rt = 0; rt < 2; ++rt)
            #pragma unroll
            for (int r = 0; r < 4; ++r) {
                float v = acc[rt][ct][r] + bv;
                x1s[wr + rt * 16 + lg * 4 + r][col] = f2bf(v > 0.f ? v : 0.f);
            }
    }
    __syncthreads();

    #pragma unroll
    for (int rt = 0; rt < 2; ++rt)
        #pragma unroll
        for (int kt = 0; kt < 4; ++kt)
            Af[rt][kt] = *(const bf16x8*)&x1s[wr + rt * 16 + lr][kt * 32 + lg * 8];
    #pragma unroll
    for (int rt = 0; rt < 2; ++rt)
        #pragma unroll
        for (int ct = 0; ct < 8; ++ct)
            acc[rt][ct] = (f32x4){0.f, 0.f, 0.f, 0.f};
    #pragma unroll
    for (int ct = 0; ct < 8; ++ct) {
        bf16x8 Bf[4];
        #pragma unroll
        for (int kt = 0; kt < 4; ++kt)
            Bf[kt] = *(const bf16x8*)&W1t[(ct * 16 + lr) * 128 + kt * 32 + lg * 8];
        #pragma unroll
        for (int kt = 0; kt < 4; ++kt) {
            acc[0][ct] = __builtin_amdgcn_mfma_f32_16x16x32_bf16(Af[0][kt], Bf[kt], acc[0][ct], 0, 0, 0);
            acc[1][ct] = __builtin_amdgcn_mfma_f32_16x16x32_bf16(Af[1][kt], Bf[kt], acc[1][ct], 0, 0, 0);
        }
    }
    __syncthreads();
    #pragma unroll
    for (int ct = 0; ct < 8; ++ct)
        #pragma unroll
        for (int rt = 0; rt < 2; ++rt)
            #pragma unroll
            for (int r = 0; r < 4; ++r)
                x1s[wr + rt * 16 + lg * 4 + r][ct * 16 + lr] = f2bf(acc[rt][ct][r]);
    __syncthreads();

    #pragma unroll
    for (int i = 0; i < 8; ++i) {
        int idx = tid + i * 256;
        int row = idx >> 4, cc = idx & 15;
        bf16x8 hv = *(const bf16x8*)&x1s[row][cc * 8];
        *(bf16x8*)&h1b[(long)(r0 + row) * 128 + cc * 8] = hv;
        int head = cc >> 2, lc = (cc & 3) * 8;
        float ps = 0.f, pd = 0.f;
        #pragma unroll
        for (int j = 0; j < 8; ++j) {
            float v = (float)hv[j];
            ps += v * attS[head * 32 + lc + j];
            pd += v * attD[head * 32 + lc + j];
        }
        ps += __shfl_xor(ps, 1); ps += __shfl_xor(ps, 2);
        pd += __shfl_xor(pd, 1); pd += __shfl_xor(pd, 2);
        if ((cc & 3) == 0) {
            aS[(r0 + row) * 4 + head] = ps;
            aD[(r0 + row) * 4 + head] = pd;
        }
    }
}

// ---- partition edges into fixed-capacity bucket regions (both keyings) ----
__global__ void part_k(const int* __restrict__ srcA, const int* __restrict__ dstA,
                       int* __restrict__ bcur_d, int* __restrict__ bcur_s,
                       int* __restrict__ pr_d, int* __restrict__ pr_s) {
    __shared__ int hd[NB], hs[NB], bd[NB], bs[NB];
    for (int i = threadIdx.x; i < NB; i += 256) { hd[i] = 0; hs[i] = 0; }
    __syncthreads();
    int e0 = blockIdx.x * CHUNK;
    int e1 = min(e0 + CHUNK, ETOT);
    for (int e = e0 + threadIdx.x; e < e1; e += 256) {
        int s, d;
        if (e < NE) { s = srcA[e]; d = dstA[e]; } else { s = d = e - NE; }
        atomicAdd(&hd[d >> SHIFT], 1);
        atomicAdd(&hs[s >> SHIFT], 1);
    }
    __syncthreads();
    for (int i = threadIdx.x; i < NB; i += 256) {
        if (hd[i]) { bd[i] = atomicAdd(&bcur_d[i], hd[i]); hd[i] = 0; }
        if (hs[i]) { bs[i] = atomicAdd(&bcur_s[i], hs[i]); hs[i] = 0; }
    }
    __syncthreads();
    for (int e = e0 + threadIdx.x; e < e1; e += 256) {
        int s, d;
        if (e < NE) { s = srcA[e]; d = dstA[e]; } else { s = d = e - NE; }
        int kd = d >> SHIFT;
        pr_d[bd[kd] + atomicAdd(&hd[kd], 1)] = ((d & (NPB - 1)) << 16) | s;
        int ks = s >> SHIFT;
        pr_s[bs[ks] + atomicAdd(&hs[ks], 1)] = ((s & (NPB - 1)) << 16) | d;
    }
}

// ---- fine sort (dst keying only): per-node {offset, degree} + csr payload ----
__global__ void fine_k(const int* __restrict__ pr, const int* __restrict__ bcur,
                       int2* __restrict__ oe, int* __restrict__ csr) {
    __shared__ int cnt[NPB], off[NPB];
    int bkt = blockIdx.x;
    int n0 = bkt << SHIFT;
    int base = bkt * CAP, end = bcur[bkt];
    int t = threadIdx.x;
    if (t < NPB) cnt[t] = 0;
    __syncthreads();
    for (int i = base + t; i < end; i += 256)
        atomicAdd(&cnt[pr[i] >> 16], 1);
    __syncthreads();
    if (t < NPB) off[t] = cnt[t];
    __syncthreads();
    for (int dd = 1; dd < NPB; dd <<= 1) {
        int y = 0;
        if (t < NPB && t >= dd) y = off[t - dd];
        __syncthreads();
        if (t < NPB) off[t] += y;
        __syncthreads();
    }
    if (t < NPB) {
        int excl = off[t] - cnt[t];
        int n = n0 + t;
        if (n < NN) oe[n] = make_int2(base + excl, cnt[t]);
        off[t] = excl;
        cnt[t] = 0;
    }
    __syncthreads();
    for (int i = base + t; i < end; i += 256) {
        int p = pr[i];
        int j = p >> 16;
        int pos = base + off[j] + atomicAdd(&cnt[j], 1);
        csr[pos] = p & 0xFFFF;
    }
}

// --- layer-1: plain-exp softmax + bf16 gather + BN/ELU + fused att2 dots -------
__global__ void gather1_k(const int* __restrict__ csr_src, const int2* __restrict__ oe_d,
                          const float* __restrict__ aS, const float* __restrict__ aD,
                          const unsigned short* __restrict__ h1b, const float* __restrict__ b1,
                          const float* __restrict__ bg, const float* __restrict__ bb,
                          const float* __restrict__ va_s, const float* __restrict__ va_d,
                          unsigned short* __restrict__ x2b, float* __restrict__ aS2,
                          float* __restrict__ aD2) {
    __shared__ float4 wst[4][64];
    __shared__ unsigned sst[4][64];
    int wv = threadIdx.x >> 6;
    int d = (blockIdx.x << 2) + wv;
    if (d >= NN) return;
    int lane = threadIdx.x & 63;
    float4 ad4 = *(const float4*)&aD[d * 4];
    int2 oe = oe_d[d];
    int o0 = oe.x, deg = oe.y, o1 = o0 + deg;

    // phase A: stage unnormalized exps + partial sums
    float s0 = 0.f, s1 = 0.f, s2 = 0.f, s3 = 0.f;
    for (int base = o0; base < o1; base += 64) {
        int e = base + lane;
        if (e < o1) {
            int s = csr_src[e];
            float4 as4 = *(const float4*)&aS[s * 4];
            float4 w;
            w.x = __expf(leaky02(as4.x + ad4.x));
            w.y = __expf(leaky02(as4.y + ad4.y));
            w.z = __expf(leaky02(as4.z + ad4.z));
            w.w = __expf(leaky02(as4.w + ad4.w));
            wst[wv][lane] = w;
            sst[wv][lane] = (unsigned)(s << 8);
            s0 += w.x; s1 += w.y; s2 += w.z; s3 += w.w;
        }
    }
    #pragma unroll
    for (int off = 32; off; off >>= 1) {
        s0 += __shfl_xor(s0, off);
        s1 += __shfl_xor(s1, off);
        s2 += __shfl_xor(s2, off);
        s3 += __shfl_xor(s3, off);
    }
    float i0 = 1.f / (s0 + 1e-16f), i1 = 1.f / (s1 + 1e-16f);
    float i2 = 1.f / (s2 + 1e-16f), i3 = 1.f / (s3 + 1e-16f);

    int k = lane & 31, half = lane >> 5;
    unsigned cb = (unsigned)(k * 8);
    int headk = k >> 3;
    const char* h1base = (const char*)h1b;
    float a0 = 0.f, a1 = 0.f, a2 = 0.f, a3 = 0.f;

    if (deg <= 64) {
        // fast path: renormalize staged exps in place, consume
        if (lane < deg) {
            float4 w = wst[wv][lane];
            w.x *= i0; w.y *= i1; w.z *= i2; w.w *= i3;
            wst[wv][lane] = w;
        }
        __threadfence_block();
        for (int t = half; t < deg; t += 2) {
            float w = ((const float*)&wst[wv][t])[headk];
            unsigned ro = sst[wv][t];
            uint2 hv = *(const uint2*)(h1base + ro + cb);
            a0 += w * __uint_as_float(hv.x << 16);
            a1 += w * __uint_as_float(hv.x & 0xFFFF0000u);
            a2 += w * __uint_as_float(hv.y << 16);
            a3 += w * __uint_as_float(hv.y & 0xFFFF0000u);
        }
    } else {
        for (int base = o0; base < o1; base += 64) {
            int e = base + lane;
            if (e < o1) {
                int s = csr_src[e];
                float4 as4 = *(const float4*)&aS[s * 4];
                float4 w;
                w.x = __expf(leaky02(as4.x + ad4.x)) * i0;
                w.y = __expf(leaky02(as4.y + ad4.y)) * i1;
                w.z = __expf(leaky02(as4.z + ad4.z)) * i2;
                w.w = __expf(leaky02(as4.w + ad4.w)) * i3;
                wst[wv][lane] = w;
                sst[wv][lane] = (unsigned)(s << 8);
            }
            __threadfence_block();
            int nst = min(64, o1 - base);
            for (int t = half; t < nst; t += 2) {
                float w = ((const float*)&wst[wv][t])[headk];
                unsigned ro = sst[wv][t];
                uint2 hv = *(const uint2*)(h1base + ro + cb);
                a0 += w * __uint_as_float(hv.x << 16);
                a1 += w * __uint_as_float(hv.x & 0xFFFF0000u);
                a2 += w * __uint_as_float(hv.y << 16);
                a3 += w * __uint_as_float(hv.y & 0xFFFF0000u);
            }
            __threadfence_block();
        }
    }
    a0 += __shfl_xor(a0, 32); a1 += __shfl_xor(a1, 32);
    a2 += __shfl_xor(a2, 32); a3 += __shfl_xor(a3, 32);

    int c = k * 4;
    float v0 = (a0 + b1[c])     * BN_K * bg[c]     + bb[c];
    float v1 = (a1 + b1[c + 1]) * BN_K * bg[c + 1] + bb[c + 1];
    float v2 = (a2 + b1[c + 2]) * BN_K * bg[c + 2] + bb[c + 2];
    float v3 = (a3 + b1[c + 3]) * BN_K * bg[c + 3] + bb[c + 3];
    v0 = v0 > 0.f ? v0 : __expf(v0) - 1.f;
    v1 = v1 > 0.f ? v1 : __expf(v1) - 1.f;
    v2 = v2 > 0.f ? v2 : __expf(v2) - 1.f;
    v3 = v3 > 0.f ? v3 : __expf(v3) - 1.f;
    if (half == 0) {
        uint2 pk;
        pk.x = (unsigned)f2bf(v0) | ((unsigned)f2bf(v1) << 16);
        pk.y = (unsigned)f2bf(v2) | ((unsigned)f2bf(v3) << 16);
        *(uint2*)&x2b[(long)d * 128 + c] = pk;
    }

    float r[8];
    #pragma unroll
    for (int h = 0; h < 4; ++h) {
        float4 vs = *(const float4*)&va_s[h * 128 + c];
        float4 vd = *(const float4*)&va_d[h * 128 + c];
        float rs = v0 * vs.x + v1 * vs.y + v2 * vs.z + v3 * vs.w;
        float rd = v0 * vd.x + v1 * vd.y + v2 * vd.z + v3 * vd.w;
        r[h]     = half ? 0.f : rs;
        r[4 + h] = half ? 0.f : rd;
    }
    #pragma unroll
    for (int off = 32; off; off >>= 1) {
        #pragma unroll
        for (int j = 0; j < 8; ++j) r[j] += __shfl_xor(r[j], off);
    }
    if (lane == 0) {
        *(float4*)&aS2[d * 4] = make_float4(r[0], r[1], r[2], r[3]);
        *(float4*)&aD2[d * 4] = make_float4(r[4], r[5], r[6], r[7]);
    }
}

// ---- layer-2 denominators, bucket-direct from pr_d: adL = {aD2, invS} ----
__global__ __launch_bounds__(512) void dsum2_k(const int* __restrict__ pr_d,
                                               const int* __restrict__ bcur_d,
                                               const float* __restrict__ aS2,
                                               const float* __restrict__ aD2,
                                               float* __restrict__ adL) {
    __shared__ float ad2s[NPB][4];
    __shared__ float sums[NPB * 4];
    int bkt = blockIdx.x, t = threadIdx.x;
    int n0 = bkt << SHIFT;
    sums[t] = 0.f;                       // 512 = NPB*4
    if (t < NPB) {
        int n = n0 + t;
        float4 v = (n < NN) ? *(const float4*)&aD2[n * 4] : make_float4(0.f, 0.f, 0.f, 0.f);
        *(float4*)&ad2s[t][0] = v;
    }
    __syncthreads();
    int base = bkt * CAP, end = bcur_d[bkt];
    for (int i = base + t; i < end; i += 512) {
        int p = pr_d[i];
        int ld = p >> 16, s = p & 0xFFFF;
        float4 as4 = *(const float4*)&aS2[s * 4];
        float4 adv = *(const float4*)&ad2s[ld][0];
        atomicAdd(&sums[ld * 4 + 0], __expf(leaky02(as4.x + adv.x)));
        atomicAdd(&sums[ld * 4 + 1], __expf(leaky02(as4.y + adv.y)));
        atomicAdd(&sums[ld * 4 + 2], __expf(leaky02(as4.z + adv.z)));
        atomicAdd(&sums[ld * 4 + 3], __expf(leaky02(as4.w + adv.w)));
    }
    __syncthreads();
    if (t < NPB) {
        int n = n0 + t;
        if (n < NN) {
            *(float4*)&adL[n * 8] = *(float4*)&ad2s[t][0];
            *(float4*)&adL[n * 8 + 4] = make_float4(
                1.f / (sums[t * 4 + 0] + 1e-16f), 1.f / (sums[t * 4 + 1] + 1e-16f),
                1.f / (sums[t * 4 + 2] + 1e-16f), 1.f / (sums[t * 4 + 3] + 1e-16f));
        }
    }
}

// ---- layer-2 per-src weights, bucket-direct from pr_s ----
__global__ __launch_bounds__(512) void waccg2_k(const int* __restrict__ pr_s,
                                                const int* __restrict__ bcur_s,
                                                const float* __restrict__ aS2,
                                                const float* __restrict__ adL,
                                                float* __restrict__ Wacc) {
    __shared__ float as2s[NPB][4];
    __shared__ float wac[NPB * 4];
    int bkt = blockIdx.x, t = threadIdx.x;
    int n0 = bkt << SHIFT;
    wac[t] = 0.f;
    if (t < NPB) {
        int n = n0 + t;
        float4 v = (n < NN) ? *(const float4*)&aS2[n * 4] : make_float4(0.f, 0.f, 0.f, 0.f);
        *(float4*)&as2s[t][0] = v;
    }
    __syncthreads();
    int base = bkt * CAP, end = bcur_s[bkt];
    for (int i = base + t; i < end; i += 512) {
        int p = pr_s[i];
        int ls = p >> 16, d = p & 0xFFFF;
        float4 adv = *(const float4*)&adL[d * 8];
        float4 iv  = *(const float4*)&adL[d * 8 + 4];
        float4 asv = *(const float4*)&as2s[ls][0];
        atomicAdd(&wac[ls * 4 + 0], __expf(leaky02(asv.x + adv.x)) * iv.x);
        atomicAdd(&wac[ls * 4 + 1], __expf(leaky02(asv.y + adv.y)) * iv.y);
        atomicAdd(&wac[ls * 4 + 2], __expf(leaky02(asv.z + adv.z)) * iv.z);
        atomicAdd(&wac[ls * 4 + 3], __expf(leaky02(asv.w + adv.w)) * iv.w);
    }
    __syncthreads();
    if (t < NPB) {
        int n = n0 + t;
        if (n < NN) {
            const float scale = 0.25f / (float)NN;
            *(float4*)&Wacc[n * 4] = make_float4(scale * wac[t * 4 + 0], scale * wac[t * 4 + 1],
                                                 scale * wac[t * 4 + 2], scale * wac[t * 4 + 3]);
        }
    }
}

// y[h,k] = sum_r Wacc[r,h] * x2[r,k]  (x2 in bf16)
__global__ void yacc_k(const float* __restrict__ Wacc, const unsigned short* __restrict__ x2b,
                       float* __restrict__ y) {
    int k2 = threadIdx.x;
    float a[8] = {};
    for (int r = blockIdx.x; r < NN; r += gridDim.x) {
        float4 w = *(const float4*)&Wacc[r * 4];
        unsigned hv = *(const unsigned*)&x2b[(long)r * 128 + k2 * 2];
        float xl = __uint_as_float(hv << 16);
        float xh = __uint_as_float(hv & 0xFFFF0000u);
        a[0] += w.x * xl; a[1] += w.x * xh;
        a[2] += w.y * xl; a[3] += w.y * xh;
        a[4] += w.z * xl; a[5] += w.z * xh;
        a[6] += w.w * xl; a[7] += w.w * xh;
    }
    int c = k2 * 2;
    atomicAdd(&y[0 * 128 + c], a[0]); atomicAdd(&y[0 * 128 + c + 1], a[1]);
    atomicAdd(&y[1 * 128 + c], a[2]); atomicAdd(&y[1 * 128 + c + 1], a[3]);
    atomicAdd(&y[2 * 128 + c], a[4]); atomicAdd(&y[2 * 128 + c + 1], a[5]);
    atomicAdd(&y[3 * 128 + c], a[6]); atomicAdd(&y[3 * 128 + c + 1], a[7]);
}

__global__ void final2_k(const float* __restrict__ y, const float* __restrict__ W2,
                         const float* __restrict__ b2, const float* __restrict__ oW,
                         const float* __restrict__ ob, float* __restrict__ out) {
    __shared__ float xm[128];
    int c = threadIdx.x;
    float t = b2[c];
    #pragma unroll
    for (int h = 0; h < 4; ++h) {
        const float* yh = y + h * 128;
        for (int k = 0; k < 128; ++k) t += yh[k] * W2[(long)k * 512 + h * 128 + c];
    }
    xm[c] = t;
    __syncthreads();
    float acc = ob[c];
    for (int k = 0; k < 128; ++k) acc += xm[k] * oW[k * 128 + c];
    out[c] = acc > 0.f ? acc : 0.f;
}

extern "C" void kernel_launch(void* const* d_in, const int* in_sizes, int n_in,
                              void* d_out, int out_size, void* d_ws, size_t ws_size,
                              hipStream_t stream) {
    const float* x0  = (const float*)d_in[0];
    const int*   ei  = (const int*)d_in[1];
    const float* pW  = (const float*)d_in[2];
    const float* pb  = (const float*)d_in[3];
    const float* W1  = (const float*)d_in[4];
    const float* as1 = (const float*)d_in[5];
    const float* ad1 = (const float*)d_in[6];
    const float* b1  = (const float*)d_in[7];
    const float* bg  = (const float*)d_in[8];
    const float* bb  = (const float*)d_in[9];
    const float* W2  = (const float*)d_in[10];
    const float* as2 = (const float*)d_in[11];
    const float* ad2 = (const float*)d_in[12];
    const float* b2  = (const float*)d_in[13];
    const float* oW  = (const float*)d_in[14];
    const float* ob  = (const float*)d_in[15];
    float* out = (float*)d_out;

    float* ws = (float*)d_ws;
    unsigned short* x0b = (unsigned short*)ws; ws += 3203072;
    unsigned short* h1b = (unsigned short*)ws; ws += 3203072;
    unsigned short* x2b = (unsigned short*)ws; ws += 3200000;
    unsigned short* pWt = (unsigned short*)ws; ws += 8192;
    unsigned short* W1t = (unsigned short*)ws; ws += 8192;
    float* aS1   = ws; ws += 200192;
    float* aD1   = ws; ws += 200192;
    float* aS2   = ws; ws += 200000;
    float* aD2   = ws; ws += 200000;
    float* adL   = ws; ws += 400000;
    float* Wacc  = ws; ws += 200000;
    float* va_s  = ws; ws += 512;
    float* va_d  = ws; ws += 512;
    float* y     = ws; ws += 512;
    int* bcur_d  = (int*)ws; ws += NB;
    int* bcur_s  = (int*)ws; ws += NB;
    int2* oe_d   = (int2*)ws; ws += 2 * NN;
    int* csr_src = (int*)ws; ws += NB * CAP;
    int* pr_d    = (int*)ws; ws += NB * CAP;
    int* pr_s    = (int*)ws; ws += NB * CAP;

    const int* srcA = ei;
    const int* dstA = ei + NE;

    dim3 blk(256);

    init_k<<<1, 512, 0, stream>>>(bcur_d, bcur_s, y);
    cvtw_k<<<CVB + 6, blk, 0, stream>>>(x0, x0b, pW, W1, pWt, W1t, W2, as2, ad2, va_s, va_d);
    part_k<<<PGRID, blk, 0, stream>>>(srcA, dstA, bcur_d, bcur_s, pr_d, pr_s);
    fine_k<<<NB, blk, 0, stream>>>(pr_d, bcur_d, oe_d, csr_src);

    fgemm_k<<<NB, blk, 0, stream>>>(x0b, pWt, W1t, pb, as1, ad1, h1b, aS1, aD1);

    gather1_k<<<12500, blk, 0, stream>>>(csr_src, oe_d, aS1, aD1, h1b, b1, bg, bb,
                                         va_s, va_d, x2b, aS2, aD2);

    dsum2_k<<<NB, 512, 0, stream>>>(pr_d, bcur_d, aS2, aD2, adL);
    waccg2_k<<<NB, 512, 0, stream>>>(pr_s, bcur_s, aS2, adL, Wacc);
    yacc_k<<<256, 64, 0, stream>>>(Wacc, x2b, y);
    final2_k<<<1, 128, 0, stream>>>(y, W2, b2, oW, ob, out);
}

// Round 11
// 396.830 us; speedup vs baseline: 1.1579x; 1.1579x over previous
//
#include <hip/hip_runtime.h>
#include <hip/hip_bf16.h>

#define NN 50000
#define NROW 50048                     // 391 * 128 padded rows
#define NE 1600000
#define ETOT (NE + NN)                 // 1,650,000 (self-loops appended)
#define BN_K 0.9999950000374997f

#define SHIFT 7
#define NPB 128
#define NB ((NN + NPB - 1) >> SHIFT)   // 391
#define CAP 5120                       // fixed bucket capacity (mean ~4221, +14 sigma)
#define CHUNK 4096
#define PGRID ((ETOT + CHUNK - 1) / CHUNK)
#define CVB (NROW * 32 / 256)          // 6256 blocks for x0 conversion

typedef __bf16 bf16x8 __attribute__((ext_vector_type(8)));
typedef float f32x4 __attribute__((ext_vector_type(4)));

__device__ __forceinline__ float leaky02(float x) { return x > 0.f ? x : 0.2f * x; }

__device__ __forceinline__ unsigned short f2bf(float f) {
    unsigned int u = __float_as_uint(f);
    u += 0x7FFFu + ((u >> 16) & 1u);
    return (unsigned short)(u >> 16);
}

// ---------------- init: bucket cursors + y ----------------
__global__ void init_k(int* __restrict__ bcur_d, int* __restrict__ bcur_s,
                       float* __restrict__ y) {
    int t = threadIdx.x;                 // 512
    if (t < NB) { bcur_d[t] = t * CAP; bcur_s[t] = t * CAP; }
    y[t] = 0.f;
}

// ---- combined prep: x0->bf16 | weight transpose->bf16 | fold va = W2^T att2 ----
__global__ void cvtw_k(const float* __restrict__ x0, unsigned short* __restrict__ x0b,
                       const float* __restrict__ pW, const float* __restrict__ W1,
                       unsigned short* __restrict__ pWt, unsigned short* __restrict__ W1t,
                       const float* __restrict__ W2, const float* __restrict__ as2,
                       const float* __restrict__ ad2, float* __restrict__ va_s,
                       float* __restrict__ va_d) {
    int b = blockIdx.x;
    if (b < CVB) {
        int g = b * 256 + threadIdx.x;
        int row = g >> 5;
        float4 v = make_float4(0.f, 0.f, 0.f, 0.f);
        if (row < NN) v = *(const float4*)&x0[(long)g * 4];
        ushort4 u;
        u.x = f2bf(v.x); u.y = f2bf(v.y); u.z = f2bf(v.z); u.w = f2bf(v.w);
        *(ushort4*)&x0b[(long)g * 4] = u;
    } else if (b < CVB + 2) {
        const float* in = (b - CVB) ? W1 : pW;
        unsigned short* outp = (b - CVB) ? W1t : pWt;
        for (int i = threadIdx.x; i < 16384; i += 256) {
            int n = i & 127, k = i >> 7;
            outp[n * 128 + k] = f2bf(in[k * 128 + n]);
        }
    } else {
        int h = b - CVB - 2;             // 4 blocks
        int k = threadIdx.x;
        if (k < 128) {
            const float* wrow = W2 + (long)k * 512 + h * 128;
            float accs = 0.f, accd = 0.f;
            for (int ci = 0; ci < 128; ++ci) {
                float w = wrow[ci];
                accs += w * as2[h * 128 + ci];
                accd += w * ad2[h * 128 + ci];
            }
            va_s[h * 128 + k] = accs;
            va_d[h * 128 + k] = accd;
        }
    }
}

// ---- fused MFMA chain: x1 = relu(x0@pW+pb); h1 = x1@W1 (bf16) + att dots ----
__global__ __launch_bounds__(256) void fgemm_k(
    const unsigned short* __restrict__ x0b, const unsigned short* __restrict__ pWt,
    const unsigned short* __restrict__ W1t, const float* __restrict__ pb,
    const float* __restrict__ attS, const float* __restrict__ attD,
    unsigned short* __restrict__ h1b, float* __restrict__ aS, float* __restrict__ aD) {
    __shared__ unsigned short x1s[128][136];
    const int tid = threadIdx.x;
    const int wv = tid >> 6, l = tid & 63;
    const int lr = l & 15, lg = l >> 4;
    const int r0 = blockIdx.x * 128;
    const int wr = wv * 32;

    bf16x8 Af[2][4];
    f32x4 acc[2][8];

    #pragma unroll
    for (int rt = 0; rt < 2; ++rt)
        #pragma unroll
        for (int kt = 0; kt < 4; ++kt)
            Af[rt][kt] = *(const bf16x8*)&x0b[(long)(r0 + wr + rt * 16 + lr) * 128 + kt * 32 + lg * 8];
    #pragma unroll
    for (int rt = 0; rt < 2; ++rt)
        #pragma unroll
        for (int ct = 0; ct < 8; ++ct)
            acc[rt][ct] = (f32x4){0.f, 0.f, 0.f, 0.f};
    #pragma unroll
    for (int ct = 0; ct < 8; ++ct) {
        bf16x8 Bf[4];
        #pragma unroll
        for (int kt = 0; kt < 4; ++kt)
            Bf[kt] = *(const bf16x8*)&pWt[(ct * 16 + lr) * 128 + kt * 32 + lg * 8];
        #pragma unroll
        for (int kt = 0; kt < 4; ++kt) {
            acc[0][ct] = __builtin_amdgcn_mfma_f32_16x16x32_bf16(Af[0][kt], Bf[kt], acc[0][ct], 0, 0, 0);
            acc[1][ct] = __builtin_amdgcn_mfma_f32_16x16x32_bf16(Af[1][kt], Bf[kt], acc[1][ct], 0, 0, 0);
        }
    }
    #pragma unroll
    for (int ct = 0; ct < 8; ++ct) {
        int col = ct * 16 + lr;
        float bv = pb[col];
        #pragma unroll
        for (int rt = 0; rt < 2; ++rt)
            #pragma unroll
            for (int r = 0; r < 4; ++r) {
                float v = acc[rt][ct][r] + bv;
                x1s[wr + rt * 16 + lg * 4 + r][col] = f2bf(v > 0.f ? v : 0.f);
            }
    }
    __syncthreads();

    #pragma unroll
    for (int rt = 0; rt < 2; ++rt)
        #pragma unroll
        for (int kt = 0; kt < 4; ++kt)
            Af[rt][kt] = *(const bf16x8*)&x1s[wr + rt * 16 + lr][kt * 32 + lg * 8];
    #pragma unroll
    for (int rt = 0; rt < 2; ++rt)
        #pragma unroll
        for (int ct = 0; ct < 8; ++ct)
            acc[rt][ct] = (f32x4){0.f, 0.f, 0.f, 0.f};
    #pragma unroll
    for (int ct = 0; ct < 8; ++ct) {
        bf16x8 Bf[4];
        #pragma unroll
        for (int kt = 0; kt < 4; ++kt)
            Bf[kt] = *(const bf16x8*)&W1t[(ct * 16 + lr) * 128 + kt * 32 + lg * 8];
        #pragma unroll
        for (int kt = 0; kt < 4; ++kt) {
            acc[0][ct] = __builtin_amdgcn_mfma_f32_16x16x32_bf16(Af[0][kt], Bf[kt], acc[0][ct], 0, 0, 0);
            acc[1][ct] = __builtin_amdgcn_mfma_f32_16x16x32_bf16(Af[1][kt], Bf[kt], acc[1][ct], 0, 0, 0);
        }
    }
    __syncthreads();
    #pragma unroll
    for (int ct = 0; ct < 8; ++ct)
        #pragma unroll
        for (int rt = 0; rt < 2; ++rt)
            #pragma unroll
            for (int r = 0; r < 4; ++r)
                x1s[wr + rt * 16 + lg * 4 + r][ct * 16 + lr] = f2bf(acc[rt][ct][r]);
    __syncthreads();

    #pragma unroll
    for (int i = 0; i < 8; ++i) {
        int idx = tid + i * 256;
        int row = idx >> 4, cc = idx & 15;
        bf16x8 hv = *(const bf16x8*)&x1s[row][cc * 8];
        *(bf16x8*)&h1b[(long)(r0 + row) * 128 + cc * 8] = hv;
        int head = cc >> 2, lc = (cc & 3) * 8;
        float ps = 0.f, pd = 0.f;
        #pragma unroll
        for (int j = 0; j < 8; ++j) {
            float v = (float)hv[j];
            ps += v * attS[head * 32 + lc + j];
            pd += v * attD[head * 32 + lc + j];
        }
        ps += __shfl_xor(ps, 1); ps += __shfl_xor(ps, 2);
        pd += __shfl_xor(pd, 1); pd += __shfl_xor(pd, 2);
        if ((cc & 3) == 0) {
            aS[(r0 + row) * 4 + head] = ps;
            aD[(r0 + row) * 4 + head] = pd;
        }
    }
}

// ---- partition with LDS-staged, bucket-sorted coalesced writes (both keyings) ----
__global__ __launch_bounds__(512) void part_k(const int* __restrict__ srcA,
                                              const int* __restrict__ dstA,
                                              int* __restrict__ bcur_d, int* __restrict__ bcur_s,
                                              int* __restrict__ pr_d, int* __restrict__ pr_s) {
    __shared__ int cnt[NB], gb[NB], lo[NB];
    __shared__ int scanbuf[512];
    __shared__ int stg[CHUNK];
    __shared__ int dbuf[CHUNK];
    int t = threadIdx.x;
    int e0 = blockIdx.x * CHUNK;
    int e1 = min(e0 + CHUNK, ETOT);
    #pragma unroll
    for (int it = 0; it < 2; ++it) {
        int* bcur = it ? bcur_s : bcur_d;
        int* pr   = it ? pr_s   : pr_d;
        for (int i = t; i < NB; i += 512) cnt[i] = 0;
        __syncthreads();
        for (int e = e0 + t; e < e1; e += 512) {
            int s, d;
            if (e < NE) { s = srcA[e]; d = dstA[e]; } else { s = d = e - NE; }
            atomicAdd(&cnt[(it ? s : d) >> SHIFT], 1);
        }
        __syncthreads();
        for (int i = t; i < NB; i += 512)
            if (cnt[i]) gb[i] = atomicAdd(&bcur[i], cnt[i]);
        scanbuf[t] = (t < NB) ? cnt[t] : 0;
        __syncthreads();
        for (int dd = 1; dd < 512; dd <<= 1) {
            int y = (t >= dd) ? scanbuf[t - dd] : 0;
            __syncthreads();
            scanbuf[t] += y;
            __syncthreads();
        }
        if (t < NB) lo[t] = scanbuf[t] - cnt[t];
        __syncthreads();
        if (t < NB) cnt[t] = lo[t];          // becomes running cursor
        __syncthreads();
        for (int e = e0 + t; e < e1; e += 512) {
            int s, d;
            if (e < NE) { s = srcA[e]; d = dstA[e]; } else { s = d = e - NE; }
            int n = it ? s : d, pay = it ? d : s;
            int key = n >> SHIFT;
            int idx = atomicAdd(&cnt[key], 1);
            stg[idx]  = ((n & (NPB - 1)) << 16) | pay;
            dbuf[idx] = gb[key] + (idx - lo[key]);
        }
        __syncthreads();
        int tot = e1 - e0;
        for (int p = t; p < tot; p += 512)
            pr[dbuf[p]] = stg[p];
        __syncthreads();
    }
}

// ---- fine sort (both keyings): per-node {offset, degree} + csr payload ----
__global__ void fine_k(const int* __restrict__ pr_d, const int* __restrict__ bcur_d,
                       int2* __restrict__ oe_d, int* __restrict__ csr_src,
                       const int* __restrict__ pr_s, const int* __restrict__ bcur_s,
                       int2* __restrict__ oe_s, int* __restrict__ csr_dst) {
    bool dk = blockIdx.x < NB;
    const int* pr    = dk ? pr_d : pr_s;
    const int* bcurb = dk ? bcur_d : bcur_s;
    int2* oe         = dk ? oe_d : oe_s;
    int* csr         = dk ? csr_src : csr_dst;
    int bkt = dk ? blockIdx.x : blockIdx.x - NB;
    __shared__ int cnt[NPB], off[NPB];
    int n0 = bkt << SHIFT;
    int base = bkt * CAP, end = bcurb[bkt];
    int t = threadIdx.x;
    if (t < NPB) cnt[t] = 0;
    __syncthreads();
    for (int i = base + t; i < end; i += 256)
        atomicAdd(&cnt[pr[i] >> 16], 1);
    __syncthreads();
    if (t < NPB) off[t] = cnt[t];
    __syncthreads();
    for (int dd = 1; dd < NPB; dd <<= 1) {
        int y = 0;
        if (t < NPB && t >= dd) y = off[t - dd];
        __syncthreads();
        if (t < NPB) off[t] += y;
        __syncthreads();
    }
    if (t < NPB) {
        int excl = off[t] - cnt[t];
        int n = n0 + t;
        if (n < NN) oe[n] = make_int2(base + excl, cnt[t]);
        off[t] = excl;
        cnt[t] = 0;
    }
    __syncthreads();
    for (int i = base + t; i < end; i += 256) {
        int p = pr[i];
        int j = p >> 16;
        int pos = base + off[j] + atomicAdd(&cnt[j], 1);
        csr[pos] = p & 0xFFFF;
    }
}

// --- layer-1: plain-exp softmax + bf16 gather + BN/ELU + fused att2 dots -------
__global__ void gather1_k(const int* __restrict__ csr_src, const int2* __restrict__ oe_d,
                          const float* __restrict__ aS, const float* __restrict__ aD,
                          const unsigned short* __restrict__ h1b, const float* __restrict__ b1,
                          const float* __restrict__ bg, const float* __restrict__ bb,
                          const float* __restrict__ va_s, const float* __restrict__ va_d,
                          unsigned short* __restrict__ x2b, float* __restrict__ aS2,
                          float* __restrict__ aD2) {
    __shared__ float4 wst[4][64];
    __shared__ unsigned sst[4][64];
    int wv = threadIdx.x >> 6;
    int d = (blockIdx.x << 2) + wv;
    if (d >= NN) return;
    int lane = threadIdx.x & 63;
    float4 ad4 = *(const float4*)&aD[d * 4];
    int2 oe = oe_d[d];
    int o0 = oe.x, deg = oe.y, o1 = o0 + deg;

    float s0 = 0.f, s1 = 0.f, s2 = 0.f, s3 = 0.f;
    for (int base = o0; base < o1; base += 64) {
        int e = base + lane;
        if (e < o1) {
            int s = csr_src[e];
            float4 as4 = *(const float4*)&aS[s * 4];
            float4 w;
            w.x = __expf(leaky02(as4.x + ad4.x));
            w.y = __expf(leaky02(as4.y + ad4.y));
            w.z = __expf(leaky02(as4.z + ad4.z));
            w.w = __expf(leaky02(as4.w + ad4.w));
            wst[wv][lane] = w;
            sst[wv][lane] = (unsigned)(s << 8);
            s0 += w.x; s1 += w.y; s2 += w.z; s3 += w.w;
        }
    }
    #pragma unroll
    for (int off = 32; off; off >>= 1) {
        s0 += __shfl_xor(s0, off);
        s1 += __shfl_xor(s1, off);
        s2 += __shfl_xor(s2, off);
        s3 += __shfl_xor(s3, off);
    }
    float i0 = 1.f / (s0 + 1e-16f), i1 = 1.f / (s1 + 1e-16f);
    float i2 = 1.f / (s2 + 1e-16f), i3 = 1.f / (s3 + 1e-16f);

    int k = lane & 31, half = lane >> 5;
    unsigned cb = (unsigned)(k * 8);
    int headk = k >> 3;
    const char* h1base = (const char*)h1b;
    float a0 = 0.f, a1 = 0.f, a2 = 0.f, a3 = 0.f;

    if (deg <= 64) {
        if (lane < deg) {
            float4 w = wst[wv][lane];
            w.x *= i0; w.y *= i1; w.z *= i2; w.w *= i3;
            wst[wv][lane] = w;
        }
        __threadfence_block();
        for (int t = half; t < deg; t += 2) {
            float w = ((const float*)&wst[wv][t])[headk];
            unsigned ro = sst[wv][t];
            uint2 hv = *(const uint2*)(h1base + ro + cb);
            a0 += w * __uint_as_float(hv.x << 16);
            a1 += w * __uint_as_float(hv.x & 0xFFFF0000u);
            a2 += w * __uint_as_float(hv.y << 16);
            a3 += w * __uint_as_float(hv.y & 0xFFFF0000u);
        }
    } else {
        for (int base = o0; base < o1; base += 64) {
            int e = base + lane;
            if (e < o1) {
                int s = csr_src[e];
                float4 as4 = *(const float4*)&aS[s * 4];
                float4 w;
                w.x = __expf(leaky02(as4.x + ad4.x)) * i0;
                w.y = __expf(leaky02(as4.y + ad4.y)) * i1;
                w.z = __expf(leaky02(as4.z + ad4.z)) * i2;
                w.w = __expf(leaky02(as4.w + ad4.w)) * i3;
                wst[wv][lane] = w;
                sst[wv][lane] = (unsigned)(s << 8);
            }
            __threadfence_block();
            int nst = min(64, o1 - base);
            for (int t = half; t < nst; t += 2) {
                float w = ((const float*)&wst[wv][t])[headk];
                unsigned ro = sst[wv][t];
                uint2 hv = *(const uint2*)(h1base + ro + cb);
                a0 += w * __uint_as_float(hv.x << 16);
                a1 += w * __uint_as_float(hv.x & 0xFFFF0000u);
                a2 += w * __uint_as_float(hv.y << 16);
                a3 += w * __uint_as_float(hv.y & 0xFFFF0000u);
            }
            __threadfence_block();
        }
    }
    a0 += __shfl_xor(a0, 32); a1 += __shfl_xor(a1, 32);
    a2 += __shfl_xor(a2, 32); a3 += __shfl_xor(a3, 32);

    int c = k * 4;
    float v0 = (a0 + b1[c])     * BN_K * bg[c]     + bb[c];
    float v1 = (a1 + b1[c + 1]) * BN_K * bg[c + 1] + bb[c + 1];
    float v2 = (a2 + b1[c + 2]) * BN_K * bg[c + 2] + bb[c + 2];
    float v3 = (a3 + b1[c + 3]) * BN_K * bg[c + 3] + bb[c + 3];
    v0 = v0 > 0.f ? v0 : __expf(v0) - 1.f;
    v1 = v1 > 0.f ? v1 : __expf(v1) - 1.f;
    v2 = v2 > 0.f ? v2 : __expf(v2) - 1.f;
    v3 = v3 > 0.f ? v3 : __expf(v3) - 1.f;
    if (half == 0) {
        uint2 pk;
        pk.x = (unsigned)f2bf(v0) | ((unsigned)f2bf(v1) << 16);
        pk.y = (unsigned)f2bf(v2) | ((unsigned)f2bf(v3) << 16);
        *(uint2*)&x2b[(long)d * 128 + c] = pk;
    }

    float r[8];
    #pragma unroll
    for (int h = 0; h < 4; ++h) {
        float4 vs = *(const float4*)&va_s[h * 128 + c];
        float4 vd = *(const float4*)&va_d[h * 128 + c];
        float rs = v0 * vs.x + v1 * vs.y + v2 * vs.z + v3 * vs.w;
        float rd = v0 * vd.x + v1 * vd.y + v2 * vd.z + v3 * vd.w;
        r[h]     = half ? 0.f : rs;
        r[4 + h] = half ? 0.f : rd;
    }
    #pragma unroll
    for (int off = 32; off; off >>= 1) {
        #pragma unroll
        for (int j = 0; j < 8; ++j) r[j] += __shfl_xor(r[j], off);
    }
    if (lane == 0) {
        *(float4*)&aS2[d * 4] = make_float4(r[0], r[1], r[2], r[3]);
        *(float4*)&aD2[d * 4] = make_float4(r[4], r[5], r[6], r[7]);
    }
}

// ---- layer-2: per-dst sum of exp (wave-per-node) -> adL = {aD2, invS} ----
__global__ void dsum_k(const int* __restrict__ csr_src, const int2* __restrict__ oe_d,
                       const float* __restrict__ aS, const float* __restrict__ aD,
                       float* __restrict__ adL) {
    int d = (blockIdx.x << 2) + (threadIdx.x >> 6);
    if (d >= NN) return;
    int lane = threadIdx.x & 63;
    float4 ad4 = *(const float4*)&aD[d * 4];
    int2 oe = oe_d[d];
    int o0 = oe.x, o1 = oe.x + oe.y;
    float s0 = 0.f, s1 = 0.f, s2 = 0.f, s3 = 0.f;
    for (int o = o0 + lane; o < o1; o += 64) {
        int s = csr_src[o];
        float4 as4 = *(const float4*)&aS[s * 4];
        s0 += __expf(leaky02(as4.x + ad4.x));
        s1 += __expf(leaky02(as4.y + ad4.y));
        s2 += __expf(leaky02(as4.z + ad4.z));
        s3 += __expf(leaky02(as4.w + ad4.w));
    }
    #pragma unroll
    for (int off = 32; off; off >>= 1) {
        s0 += __shfl_xor(s0, off);
        s1 += __shfl_xor(s1, off);
        s2 += __shfl_xor(s2, off);
        s3 += __shfl_xor(s3, off);
    }
    if (lane == 0) {
        *(float4*)&adL[d * 8]     = ad4;
        *(float4*)&adL[d * 8 + 4] = make_float4(1.f / (s0 + 1e-16f), 1.f / (s1 + 1e-16f),
                                                1.f / (s2 + 1e-16f), 1.f / (s3 + 1e-16f));
    }
}

// ---- layer-2: per-src weight (wave-per-node) via src-CSR ----
__global__ void waccg_k(const int* __restrict__ csr_dst, const int2* __restrict__ oe_s,
                        const float* __restrict__ aS, const float* __restrict__ adL,
                        float* __restrict__ Wacc) {
    int s = (blockIdx.x << 2) + (threadIdx.x >> 6);
    if (s >= NN) return;
    int lane = threadIdx.x & 63;
    float4 as4 = *(const float4*)&aS[s * 4];
    int2 oe = oe_s[s];
    int o0 = oe.x, o1 = oe.x + oe.y;
    float a0 = 0.f, a1 = 0.f, a2 = 0.f, a3 = 0.f;
    for (int o = o0 + lane; o < o1; o += 64) {
        int d = csr_dst[o];
        float4 ad4 = *(const float4*)&adL[d * 8];
        float4 iv  = *(const float4*)&adL[d * 8 + 4];
        a0 += __expf(leaky02(as4.x + ad4.x)) * iv.x;
        a1 += __expf(leaky02(as4.y + ad4.y)) * iv.y;
        a2 += __expf(leaky02(as4.z + ad4.z)) * iv.z;
        a3 += __expf(leaky02(as4.w + ad4.w)) * iv.w;
    }
    #pragma unroll
    for (int off = 32; off; off >>= 1) {
        a0 += __shfl_xor(a0, off);
        a1 += __shfl_xor(a1, off);
        a2 += __shfl_xor(a2, off);
        a3 += __shfl_xor(a3, off);
    }
    if (lane == 0) {
        const float scale = 0.25f / (float)NN;
        *(float4*)&Wacc[s * 4] = make_float4(scale * a0, scale * a1, scale * a2, scale * a3);
    }
}

// y[h,k] = sum_r Wacc[r,h] * x2[r,k]  (x2 in bf16)
__global__ void yacc_k(const float* __restrict__ Wacc, const unsigned short* __restrict__ x2b,
                       float* __restrict__ y) {
    int k2 = threadIdx.x;
    float a[8] = {};
    for (int r = blockIdx.x; r < NN; r += gridDim.x) {
        float4 w = *(const float4*)&Wacc[r * 4];
        unsigned hv = *(const unsigned*)&x2b[(long)r * 128 + k2 * 2];
        float xl = __uint_as_float(hv << 16);
        float xh = __uint_as_float(hv & 0xFFFF0000u);
        a[0] += w.x * xl; a[1] += w.x * xh;
        a[2] += w.y * xl; a[3] += w.y * xh;
        a[4] += w.z * xl; a[5] += w.z * xh;
        a[6] += w.w * xl; a[7] += w.w * xh;
    }
    int c = k2 * 2;
    atomicAdd(&y[0 * 128 + c], a[0]); atomicAdd(&y[0 * 128 + c + 1], a[1]);
    atomicAdd(&y[1 * 128 + c], a[2]); atomicAdd(&y[1 * 128 + c + 1], a[3]);
    atomicAdd(&y[2 * 128 + c], a[4]); atomicAdd(&y[2 * 128 + c + 1], a[5]);
    atomicAdd(&y[3 * 128 + c], a[6]); atomicAdd(&y[3 * 128 + c + 1], a[7]);
}

__global__ void final2_k(const float* __restrict__ y, const float* __restrict__ W2,
                         const float* __restrict__ b2, const float* __restrict__ oW,
                         const float* __restrict__ ob, float* __restrict__ out) {
    __shared__ float xm[128];
    int c = threadIdx.x;
    float t = b2[c];
    #pragma unroll
    for (int h = 0; h < 4; ++h) {
        const float* yh = y + h * 128;
        for (int k = 0; k < 128; ++k) t += yh[k] * W2[(long)k * 512 + h * 128 + c];
    }
    xm[c] = t;
    __syncthreads();
    float acc = ob[c];
    for (int k = 0; k < 128; ++k) acc += xm[k] * oW[k * 128 + c];
    out[c] = acc > 0.f ? acc : 0.f;
}

extern "C" void kernel_launch(void* const* d_in, const int* in_sizes, int n_in,
                              void* d_out, int out_size, void* d_ws, size_t ws_size,
                              hipStream_t stream) {
    const float* x0  = (const float*)d_in[0];
    const int*   ei  = (const int*)d_in[1];
    const float* pW  = (const float*)d_in[2];
    const float* pb  = (const float*)d_in[3];
    const float* W1  = (const float*)d_in[4];
    const float* as1 = (const float*)d_in[5];
    const float* ad1 = (const float*)d_in[6];
    const float* b1  = (const float*)d_in[7];
    const float* bg  = (const float*)d_in[8];
    const float* bb  = (const float*)d_in[9];
    const float* W2  = (const float*)d_in[10];
    const float* as2 = (const float*)d_in[11];
    const float* ad2 = (const float*)d_in[12];
    const float* b2  = (const float*)d_in[13];
    const float* oW  = (const float*)d_in[14];
    const float* ob  = (const float*)d_in[15];
    float* out = (float*)d_out;

    float* ws = (float*)d_ws;
    unsigned short* x0b = (unsigned short*)ws; ws += 3203072;
    unsigned short* h1b = (unsigned short*)ws; ws += 3203072;
    unsigned short* x2b = (unsigned short*)ws; ws += 3200000;
    unsigned short* pWt = (unsigned short*)ws; ws += 8192;
    unsigned short* W1t = (unsigned short*)ws; ws += 8192;
    float* aS1   = ws; ws += 200192;
    float* aD1   = ws; ws += 200192;
    float* aS2   = ws; ws += 200000;
    float* aD2   = ws; ws += 200000;
    float* adL   = ws; ws += 400000;
    float* Wacc  = ws; ws += 200000;
    float* va_s  = ws; ws += 512;
    float* va_d  = ws; ws += 512;
    float* y     = ws; ws += 512;
    int* bcur_d  = (int*)ws; ws += NB;
    int* bcur_s  = (int*)ws; ws += NB;
    int2* oe_d   = (int2*)ws; ws += 2 * NN;
    int2* oe_s   = (int2*)ws; ws += 2 * NN;
    int* csr_src = (int*)ws; ws += NB * CAP;
    int* csr_dst = (int*)ws; ws += NB * CAP;
    int* pr_d    = (int*)ws; ws += NB * CAP;
    int* pr_s    = (int*)ws; ws += NB * CAP;

    const int* srcA = ei;
    const int* dstA = ei + NE;

    dim3 blk(256);

    init_k<<<1, 512, 0, stream>>>(bcur_d, bcur_s, y);
    cvtw_k<<<CVB + 6, blk, 0, stream>>>(x0, x0b, pW, W1, pWt, W1t, W2, as2, ad2, va_s, va_d);
    part_k<<<PGRID, 512, 0, stream>>>(srcA, dstA, bcur_d, bcur_s, pr_d, pr_s);
    fine_k<<<2 * NB, blk, 0, stream>>>(pr_d, bcur_d, oe_d, csr_src,
                                       pr_s, bcur_s, oe_s, csr_dst);

    fgemm_k<<<NB, blk, 0, stream>>>(x0b, pWt, W1t, pb, as1, ad1, h1b, aS1, aD1);

    gather1_k<<<12500, blk, 0, stream>>>(csr_src, oe_d, aS1, aD1, h1b, b1, bg, bb,
                                         va_s, va_d, x2b, aS2, aD2);

    dsum_k<<<12500, blk, 0, stream>>>(csr_src, oe_d, aS2, aD2, adL);
    waccg_k<<<12500, blk, 0, stream>>>(csr_dst, oe_s, aS2, adL, Wacc);
    yacc_k<<<256, 64, 0, stream>>>(Wacc, x2b, y);
    final2_k<<<1, 128, 0, stream>>>(y, W2, b2, oW, ob, out);
}

// Round 12
// 378.736 us; speedup vs baseline: 1.2132x; 1.0478x over previous
//
#include <hip/hip_runtime.h>
#include <hip/hip_bf16.h>

#define NN 50000
#define NE 1600000
#define ETOT (NE + NN)                 // 1,650,000 (self-loops appended)
#define BN_K 0.9999950000374997f

#define SHIFT 7
#define NPB 128
#define NB ((NN + NPB - 1) >> SHIFT)   // 391
#define CAP 5120                       // fixed bucket capacity (mean ~4221, +14 sigma)
#define CHUNK 3072
#define PGRID ((ETOT + CHUNK - 1) / CHUNK)   // 538

typedef __bf16 bf16x8 __attribute__((ext_vector_type(8)));
typedef float f32x4 __attribute__((ext_vector_type(4)));

__device__ __forceinline__ float leaky02(float x) { return x > 0.f ? x : 0.2f * x; }

__device__ __forceinline__ unsigned short f2bf(float f) {
    unsigned int u = __float_as_uint(f);
    u += 0x7FFFu + ((u >> 16) & 1u);
    return (unsigned short)(u >> 16);
}

// ---- prep: weight transpose->bf16 | fold va = W2^T att2 | init cursors+y ----
__global__ void prep_k(const float* __restrict__ pW, const float* __restrict__ W1,
                       unsigned short* __restrict__ pWt, unsigned short* __restrict__ W1t,
                       const float* __restrict__ W2, const float* __restrict__ as2,
                       const float* __restrict__ ad2, float* __restrict__ va_s,
                       float* __restrict__ va_d, int* __restrict__ bcur_d,
                       int* __restrict__ bcur_s, float* __restrict__ y) {
    int b = blockIdx.x;
    int t = threadIdx.x;
    if (b < 2) {
        const float* in = b ? W1 : pW;
        unsigned short* outp = b ? W1t : pWt;
        for (int i = t; i < 16384; i += 256) {
            int n = i & 127, k = i >> 7;
            outp[n * 128 + k] = f2bf(in[k * 128 + n]);
        }
    } else if (b < 6) {
        int h = b - 2;
        if (t < 128) {
            const float* wrow = W2 + (long)t * 512 + h * 128;
            float accs = 0.f, accd = 0.f;
            for (int ci = 0; ci < 128; ++ci) {
                float w = wrow[ci];
                accs += w * as2[h * 128 + ci];
                accd += w * ad2[h * 128 + ci];
            }
            va_s[h * 128 + t] = accs;
            va_d[h * 128 + t] = accd;
        }
    } else {
        for (int i = t; i < NB; i += 256) { bcur_d[i] = i * CAP; bcur_s[i] = i * CAP; }
        for (int i = t; i < 512; i += 256) y[i] = 0.f;
    }
}

// ---- fused MFMA chain: x1 = relu(x0@pW+pb); h1 = x1@W1 (bf16) + att dots ----
// x0 read directly as fp32 and converted in-register (no cvt pass).
__global__ __launch_bounds__(256) void fgemm_k(
    const float* __restrict__ x0, const unsigned short* __restrict__ pWt,
    const unsigned short* __restrict__ W1t, const float* __restrict__ pb,
    const float* __restrict__ attS, const float* __restrict__ attD,
    unsigned short* __restrict__ h1b, float* __restrict__ aS, float* __restrict__ aD) {
    __shared__ unsigned short x1s[128][136];
    const int tid = threadIdx.x;
    const int wv = tid >> 6, l = tid & 63;
    const int lr = l & 15, lg = l >> 4;
    const int r0 = blockIdx.x * 128;
    const int wr = wv * 32;

    bf16x8 Af[2][4];
    f32x4 acc[2][8];

    // ---- GEMM1: A fragments from fp32 x0 with inline bf16 convert ----
    #pragma unroll
    for (int rt = 0; rt < 2; ++rt) {
        int row = r0 + wr + rt * 16 + lr;
        #pragma unroll
        for (int kt = 0; kt < 4; ++kt) {
            bf16x8 a;
            if (row < NN) {
                const float* p = &x0[(long)row * 128 + kt * 32 + lg * 8];
                float4 v0 = *(const float4*)p;
                float4 v1 = *(const float4*)(p + 4);
                a[0] = (__bf16)v0.x; a[1] = (__bf16)v0.y; a[2] = (__bf16)v0.z; a[3] = (__bf16)v0.w;
                a[4] = (__bf16)v1.x; a[5] = (__bf16)v1.y; a[6] = (__bf16)v1.z; a[7] = (__bf16)v1.w;
            } else {
                #pragma unroll
                for (int j = 0; j < 8; ++j) a[j] = (__bf16)0.f;
            }
            Af[rt][kt] = a;
        }
    }
    #pragma unroll
    for (int rt = 0; rt < 2; ++rt)
        #pragma unroll
        for (int ct = 0; ct < 8; ++ct)
            acc[rt][ct] = (f32x4){0.f, 0.f, 0.f, 0.f};
    #pragma unroll
    for (int ct = 0; ct < 8; ++ct) {
        bf16x8 Bf[4];
        #pragma unroll
        for (int kt = 0; kt < 4; ++kt)
            Bf[kt] = *(const bf16x8*)&pWt[(ct * 16 + lr) * 128 + kt * 32 + lg * 8];
        #pragma unroll
        for (int kt = 0; kt < 4; ++kt) {
            acc[0][ct] = __builtin_amdgcn_mfma_f32_16x16x32_bf16(Af[0][kt], Bf[kt], acc[0][ct], 0, 0, 0);
            acc[1][ct] = __builtin_amdgcn_mfma_f32_16x16x32_bf16(Af[1][kt], Bf[kt], acc[1][ct], 0, 0, 0);
        }
    }
    #pragma unroll
    for (int ct = 0; ct < 8; ++ct) {
        int col = ct * 16 + lr;
        float bv = pb[col];
        #pragma unroll
        for (int rt = 0; rt < 2; ++rt)
            #pragma unroll
            for (int r = 0; r < 4; ++r) {
                float v = acc[rt][ct][r] + bv;
                x1s[wr + rt * 16 + lg * 4 + r][col] = f2bf(v > 0.f ? v : 0.f);
            }
    }
    __syncthreads();

    // ---- GEMM2 ----
    #pragma unroll
    for (int rt = 0; rt < 2; ++rt)
        #pragma unroll
        for (int kt = 0; kt < 4; ++kt)
            Af[rt][kt] = *(const bf16x8*)&x1s[wr + rt * 16 + lr][kt * 32 + lg * 8];
    #pragma unroll
    for (int rt = 0; rt < 2; ++rt)
        #pragma unroll
        for (int ct = 0; ct < 8; ++ct)
            acc[rt][ct] = (f32x4){0.f, 0.f, 0.f, 0.f};
    #pragma unroll
    for (int ct = 0; ct < 8; ++ct) {
        bf16x8 Bf[4];
        #pragma unroll
        for (int kt = 0; kt < 4; ++kt)
            Bf[kt] = *(const bf16x8*)&W1t[(ct * 16 + lr) * 128 + kt * 32 + lg * 8];
        #pragma unroll
        for (int kt = 0; kt < 4; ++kt) {
            acc[0][ct] = __builtin_amdgcn_mfma_f32_16x16x32_bf16(Af[0][kt], Bf[kt], acc[0][ct], 0, 0, 0);
            acc[1][ct] = __builtin_amdgcn_mfma_f32_16x16x32_bf16(Af[1][kt], Bf[kt], acc[1][ct], 0, 0, 0);
        }
    }
    __syncthreads();
    #pragma unroll
    for (int ct = 0; ct < 8; ++ct)
        #pragma unroll
        for (int rt = 0; rt < 2; ++rt)
            #pragma unroll
            for (int r = 0; r < 4; ++r)
                x1s[wr + rt * 16 + lg * 4 + r][ct * 16 + lr] = f2bf(acc[rt][ct][r]);
    __syncthreads();

    #pragma unroll
    for (int i = 0; i < 8; ++i) {
        int idx = tid + i * 256;
        int row = idx >> 4, cc = idx & 15;
        bf16x8 hv = *(const bf16x8*)&x1s[row][cc * 8];
        *(bf16x8*)&h1b[(long)(r0 + row) * 128 + cc * 8] = hv;
        int head = cc >> 2, lc = (cc & 3) * 8;
        float ps = 0.f, pd = 0.f;
        #pragma unroll
        for (int j = 0; j < 8; ++j) {
            float v = (float)hv[j];
            ps += v * attS[head * 32 + lc + j];
            pd += v * attD[head * 32 + lc + j];
        }
        ps += __shfl_xor(ps, 1); ps += __shfl_xor(ps, 2);
        pd += __shfl_xor(pd, 1); pd += __shfl_xor(pd, 2);
        if ((cc & 3) == 0) {
            aS[(r0 + row) * 4 + head] = ps;
            aD[(r0 + row) * 4 + head] = pd;
        }
    }
}

// ---- partition: single pass, both keyings, LDS-staged coalesced writes ----
__global__ __launch_bounds__(512) void part_k(const int* __restrict__ srcA,
                                              const int* __restrict__ dstA,
                                              int* __restrict__ bcur_d, int* __restrict__ bcur_s,
                                              int* __restrict__ pr_d, int* __restrict__ pr_s) {
    __shared__ int cd[NB], cs[NB], gbd[NB], gbs[NB], lod[NB], los[NB];
    __shared__ int scanbuf[512];
    __shared__ int stg_d[CHUNK], db_d[CHUNK], stg_s[CHUNK], db_s[CHUNK];
    int t = threadIdx.x;
    int e0 = blockIdx.x * CHUNK;
    int e1 = min(e0 + CHUNK, ETOT);
    for (int i = t; i < NB; i += 512) { cd[i] = 0; cs[i] = 0; }
    __syncthreads();
    for (int e = e0 + t; e < e1; e += 512) {
        int s, d;
        if (e < NE) { s = srcA[e]; d = dstA[e]; } else { s = d = e - NE; }
        atomicAdd(&cd[d >> SHIFT], 1);
        atomicAdd(&cs[s >> SHIFT], 1);
    }
    __syncthreads();
    for (int i = t; i < NB; i += 512) {
        if (cd[i]) gbd[i] = atomicAdd(&bcur_d[i], cd[i]);
        if (cs[i]) gbs[i] = atomicAdd(&bcur_s[i], cs[i]);
    }
    scanbuf[t] = (t < NB) ? cd[t] : 0;
    __syncthreads();
    for (int dd = 1; dd < 512; dd <<= 1) {
        int yv = (t >= dd) ? scanbuf[t - dd] : 0;
        __syncthreads();
        scanbuf[t] += yv;
        __syncthreads();
    }
    if (t < NB) lod[t] = scanbuf[t] - cd[t];
    __syncthreads();
    scanbuf[t] = (t < NB) ? cs[t] : 0;
    __syncthreads();
    for (int dd = 1; dd < 512; dd <<= 1) {
        int yv = (t >= dd) ? scanbuf[t - dd] : 0;
        __syncthreads();
        scanbuf[t] += yv;
        __syncthreads();
    }
    if (t < NB) los[t] = scanbuf[t] - cs[t];
    __syncthreads();
    if (t < NB) { cd[t] = lod[t]; cs[t] = los[t]; }
    __syncthreads();
    for (int e = e0 + t; e < e1; e += 512) {
        int s, d;
        if (e < NE) { s = srcA[e]; d = dstA[e]; } else { s = d = e - NE; }
        int kd = d >> SHIFT;
        int id = atomicAdd(&cd[kd], 1);
        stg_d[id] = ((d & (NPB - 1)) << 16) | s;
        db_d[id]  = gbd[kd] + (id - lod[kd]);
        int ks = s >> SHIFT;
        int is = atomicAdd(&cs[ks], 1);
        stg_s[is] = ((s & (NPB - 1)) << 16) | d;
        db_s[is]  = gbs[ks] + (is - los[ks]);
    }
    __syncthreads();
    int tot = e1 - e0;
    for (int p = t; p < tot; p += 512) {
        pr_d[db_d[p]] = stg_d[p];
        pr_s[db_s[p]] = stg_s[p];
    }
}

// ---- fine sort (both keyings): per-node {offset, degree} + csr payload ----
__global__ __launch_bounds__(512) void fine_k(
        const int* __restrict__ pr_d, const int* __restrict__ bcur_d,
        int2* __restrict__ oe_d, int* __restrict__ csr_src,
        const int* __restrict__ pr_s, const int* __restrict__ bcur_s,
        int2* __restrict__ oe_s, int* __restrict__ csr_dst) {
    bool dk = blockIdx.x < NB;
    const int* pr    = dk ? pr_d : pr_s;
    const int* bcurb = dk ? bcur_d : bcur_s;
    int2* oe         = dk ? oe_d : oe_s;
    int* csr         = dk ? csr_src : csr_dst;
    int bkt = dk ? blockIdx.x : blockIdx.x - NB;
    __shared__ int cnt[NPB], off[NPB];
    int n0 = bkt << SHIFT;
    int base = bkt * CAP, end = bcurb[bkt];
    int t = threadIdx.x;
    if (t < NPB) cnt[t] = 0;
    __syncthreads();
    for (int i = base + t; i < end; i += 512)
        atomicAdd(&cnt[pr[i] >> 16], 1);
    __syncthreads();
    if (t < NPB) off[t] = cnt[t];
    __syncthreads();
    for (int dd = 1; dd < NPB; dd <<= 1) {
        int yv = 0;
        if (t < NPB && t >= dd) yv = off[t - dd];
        __syncthreads();
        if (t < NPB) off[t] += yv;
        __syncthreads();
    }
    if (t < NPB) {
        int excl = off[t] - cnt[t];
        int n = n0 + t;
        if (n < NN) oe[n] = make_int2(base + excl, cnt[t]);
        off[t] = excl;
        cnt[t] = 0;
    }
    __syncthreads();
    for (int i = base + t; i < end; i += 512) {
        int p = pr[i];
        int j = p >> 16;
        int pos = base + off[j] + atomicAdd(&cnt[j], 1);
        csr[pos] = p & 0xFFFF;
    }
}

// --- layer-1: plain-exp softmax + bf16 gather + BN/ELU + fused att2 dots -------
__global__ void gather1_k(const int* __restrict__ csr_src, const int2* __restrict__ oe_d,
                          const float* __restrict__ aS, const float* __restrict__ aD,
                          const unsigned short* __restrict__ h1b, const float* __restrict__ b1,
                          const float* __restrict__ bg, const float* __restrict__ bb,
                          const float* __restrict__ va_s, const float* __restrict__ va_d,
                          unsigned short* __restrict__ x2b, float* __restrict__ aS2,
                          float* __restrict__ aD2) {
    __shared__ float4 wst[4][64];
    __shared__ unsigned sst[4][64];
    int wv = threadIdx.x >> 6;
    int d = (blockIdx.x << 2) + wv;
    if (d >= NN) return;
    int lane = threadIdx.x & 63;
    float4 ad4 = *(const float4*)&aD[d * 4];
    int2 oe = oe_d[d];
    int o0 = oe.x, deg = oe.y, o1 = o0 + deg;

    float s0 = 0.f, s1 = 0.f, s2 = 0.f, s3 = 0.f;
    for (int base = o0; base < o1; base += 64) {
        int e = base + lane;
        if (e < o1) {
            int s = csr_src[e];
            float4 as4 = *(const float4*)&aS[s * 4];
            float4 w;
            w.x = __expf(leaky02(as4.x + ad4.x));
            w.y = __expf(leaky02(as4.y + ad4.y));
            w.z = __expf(leaky02(as4.z + ad4.z));
            w.w = __expf(leaky02(as4.w + ad4.w));
            wst[wv][lane] = w;
            sst[wv][lane] = (unsigned)(s << 8);
            s0 += w.x; s1 += w.y; s2 += w.z; s3 += w.w;
        }
    }
    #pragma unroll
    for (int off = 32; off; off >>= 1) {
        s0 += __shfl_xor(s0, off);
        s1 += __shfl_xor(s1, off);
        s2 += __shfl_xor(s2, off);
        s3 += __shfl_xor(s3, off);
    }
    float i0 = 1.f / (s0 + 1e-16f), i1 = 1.f / (s1 + 1e-16f);
    float i2 = 1.f / (s2 + 1e-16f), i3 = 1.f / (s3 + 1e-16f);

    int k = lane & 31, half = lane >> 5;
    unsigned cb = (unsigned)(k * 8);
    int headk = k >> 3;
    const char* h1base = (const char*)h1b;
    float a0 = 0.f, a1 = 0.f, a2 = 0.f, a3 = 0.f;

    if (deg <= 64) {
        if (lane < deg) {
            float4 w = wst[wv][lane];
            w.x *= i0; w.y *= i1; w.z *= i2; w.w *= i3;
            wst[wv][lane] = w;
        }
        __threadfence_block();
        for (int t = half; t < deg; t += 2) {
            float w = ((const float*)&wst[wv][t])[headk];
            unsigned ro = sst[wv][t];
            uint2 hv = *(const uint2*)(h1base + ro + cb);
            a0 += w * __uint_as_float(hv.x << 16);
            a1 += w * __uint_as_float(hv.x & 0xFFFF0000u);
            a2 += w * __uint_as_float(hv.y << 16);
            a3 += w * __uint_as_float(hv.y & 0xFFFF0000u);
        }
    } else {
        for (int base = o0; base < o1; base += 64) {
            int e = base + lane;
            if (e < o1) {
                int s = csr_src[e];
                float4 as4 = *(const float4*)&aS[s * 4];
                float4 w;
                w.x = __expf(leaky02(as4.x + ad4.x)) * i0;
                w.y = __expf(leaky02(as4.y + ad4.y)) * i1;
                w.z = __expf(leaky02(as4.z + ad4.z)) * i2;
                w.w = __expf(leaky02(as4.w + ad4.w)) * i3;
                wst[wv][lane] = w;
                sst[wv][lane] = (unsigned)(s << 8);
            }
            __threadfence_block();
            int nst = min(64, o1 - base);
            for (int t = half; t < nst; t += 2) {
                float w = ((const float*)&wst[wv][t])[headk];
                unsigned ro = sst[wv][t];
                uint2 hv = *(const uint2*)(h1base + ro + cb);
                a0 += w * __uint_as_float(hv.x << 16);
                a1 += w * __uint_as_float(hv.x & 0xFFFF0000u);
                a2 += w * __uint_as_float(hv.y << 16);
                a3 += w * __uint_as_float(hv.y & 0xFFFF0000u);
            }
            __threadfence_block();
        }
    }
    a0 += __shfl_xor(a0, 32); a1 += __shfl_xor(a1, 32);
    a2 += __shfl_xor(a2, 32); a3 += __shfl_xor(a3, 32);

    int c = k * 4;
    float v0 = (a0 + b1[c])     * BN_K * bg[c]     + bb[c];
    float v1 = (a1 + b1[c + 1]) * BN_K * bg[c + 1] + bb[c + 1];
    float v2 = (a2 + b1[c + 2]) * BN_K * bg[c + 2] + bb[c + 2];
    float v3 = (a3 + b1[c + 3]) * BN_K * bg[c + 3] + bb[c + 3];
    v0 = v0 > 0.f ? v0 : __expf(v0) - 1.f;
    v1 = v1 > 0.f ? v1 : __expf(v1) - 1.f;
    v2 = v2 > 0.f ? v2 : __expf(v2) - 1.f;
    v3 = v3 > 0.f ? v3 : __expf(v3) - 1.f;
    if (half == 0) {
        uint2 pk;
        pk.x = (unsigned)f2bf(v0) | ((unsigned)f2bf(v1) << 16);
        pk.y = (unsigned)f2bf(v2) | ((unsigned)f2bf(v3) << 16);
        *(uint2*)&x2b[(long)d * 128 + c] = pk;
    }

    float r[8];
    #pragma unroll
    for (int h = 0; h < 4; ++h) {
        float4 vs = *(const float4*)&va_s[h * 128 + c];
        float4 vd = *(const float4*)&va_d[h * 128 + c];
        float rs = v0 * vs.x + v1 * vs.y + v2 * vs.z + v3 * vs.w;
        float rd = v0 * vd.x + v1 * vd.y + v2 * vd.z + v3 * vd.w;
        r[h]     = half ? 0.f : rs;
        r[4 + h] = half ? 0.f : rd;
    }
    #pragma unroll
    for (int off = 32; off; off >>= 1) {
        #pragma unroll
        for (int j = 0; j < 8; ++j) r[j] += __shfl_xor(r[j], off);
    }
    if (lane == 0) {
        *(float4*)&aS2[d * 4] = make_float4(r[0], r[1], r[2], r[3]);
        *(float4*)&aD2[d * 4] = make_float4(r[4], r[5], r[6], r[7]);
    }
}

// ---- layer-2: per-dst sum of exp (wave-per-node) -> adL = {aD2, invS} ----
__global__ void dsum_k(const int* __restrict__ csr_src, const int2* __restrict__ oe_d,
                       const float* __restrict__ aS, const float* __restrict__ aD,
                       float* __restrict__ adL) {
    int d = (blockIdx.x << 2) + (threadIdx.x >> 6);
    if (d >= NN) return;
    int lane = threadIdx.x & 63;
    float4 ad4 = *(const float4*)&aD[d * 4];
    int2 oe = oe_d[d];
    int o0 = oe.x, o1 = oe.x + oe.y;
    float s0 = 0.f, s1 = 0.f, s2 = 0.f, s3 = 0.f;
    for (int o = o0 + lane; o < o1; o += 64) {
        int s = csr_src[o];
        float4 as4 = *(const float4*)&aS[s * 4];
        s0 += __expf(leaky02(as4.x + ad4.x));
        s1 += __expf(leaky02(as4.y + ad4.y));
        s2 += __expf(leaky02(as4.z + ad4.z));
        s3 += __expf(leaky02(as4.w + ad4.w));
    }
    #pragma unroll
    for (int off = 32; off; off >>= 1) {
        s0 += __shfl_xor(s0, off);
        s1 += __shfl_xor(s1, off);
        s2 += __shfl_xor(s2, off);
        s3 += __shfl_xor(s3, off);
    }
    if (lane == 0) {
        *(float4*)&adL[d * 8]     = ad4;
        *(float4*)&adL[d * 8 + 4] = make_float4(1.f / (s0 + 1e-16f), 1.f / (s1 + 1e-16f),
                                                1.f / (s2 + 1e-16f), 1.f / (s3 + 1e-16f));
    }
}

// ---- layer-2: per-src weight (wave-per-node) via src-CSR ----
__global__ void waccg_k(const int* __restrict__ csr_dst, const int2* __restrict__ oe_s,
                        const float* __restrict__ aS, const float* __restrict__ adL,
                        float* __restrict__ Wacc) {
    int s = (blockIdx.x << 2) + (threadIdx.x >> 6);
    if (s >= NN) return;
    int lane = threadIdx.x & 63;
    float4 as4 = *(const float4*)&aS[s * 4];
    int2 oe = oe_s[s];
    int o0 = oe.x, o1 = oe.x + oe.y;
    float a0 = 0.f, a1 = 0.f, a2 = 0.f, a3 = 0.f;
    for (int o = o0 + lane; o < o1; o += 64) {
        int d = csr_dst[o];
        float4 ad4 = *(const float4*)&adL[d * 8];
        float4 iv  = *(const float4*)&adL[d * 8 + 4];
        a0 += __expf(leaky02(as4.x + ad4.x)) * iv.x;
        a1 += __expf(leaky02(as4.y + ad4.y)) * iv.y;
        a2 += __expf(leaky02(as4.z + ad4.z)) * iv.z;
        a3 += __expf(leaky02(as4.w + ad4.w)) * iv.w;
    }
    #pragma unroll
    for (int off = 32; off; off >>= 1) {
        a0 += __shfl_xor(a0, off);
        a1 += __shfl_xor(a1, off);
        a2 += __shfl_xor(a2, off);
        a3 += __shfl_xor(a3, off);
    }
    if (lane == 0) {
        const float scale = 0.25f / (float)NN;
        *(float4*)&Wacc[s * 4] = make_float4(scale * a0, scale * a1, scale * a2, scale * a3);
    }
}

// y[h,k] = sum_r Wacc[r,h] * x2[r,k]  (x2 in bf16)
__global__ void yacc_k(const float* __restrict__ Wacc, const unsigned short* __restrict__ x2b,
                       float* __restrict__ y) {
    int k2 = threadIdx.x;
    float a[8] = {};
    for (int r = blockIdx.x; r < NN; r += gridDim.x) {
        float4 w = *(const float4*)&Wacc[r * 4];
        unsigned hv = *(const unsigned*)&x2b[(long)r * 128 + k2 * 2];
        float xl = __uint_as_float(hv << 16);
        float xh = __uint_as_float(hv & 0xFFFF0000u);
        a[0] += w.x * xl; a[1] += w.x * xh;
        a[2] += w.y * xl; a[3] += w.y * xh;
        a[4] += w.z * xl; a[5] += w.z * xh;
        a[6] += w.w * xl; a[7] += w.w * xh;
    }
    int c = k2 * 2;
    atomicAdd(&y[0 * 128 + c], a[0]); atomicAdd(&y[0 * 128 + c + 1], a[1]);
    atomicAdd(&y[1 * 128 + c], a[2]); atomicAdd(&y[1 * 128 + c + 1], a[3]);
    atomicAdd(&y[2 * 128 + c], a[4]); atomicAdd(&y[2 * 128 + c + 1], a[5]);
    atomicAdd(&y[3 * 128 + c], a[6]); atomicAdd(&y[3 * 128 + c + 1], a[7]);
}

__global__ void final2_k(const float* __restrict__ y, const float* __restrict__ W2,
                         const float* __restrict__ b2, const float* __restrict__ oW,
                         const float* __restrict__ ob, float* __restrict__ out) {
    __shared__ float xm[128];
    int c = threadIdx.x;
    float t = b2[c];
    #pragma unroll
    for (int h = 0; h < 4; ++h) {
        const float* yh = y + h * 128;
        for (int k = 0; k < 128; ++k) t += yh[k] * W2[(long)k * 512 + h * 128 + c];
    }
    xm[c] = t;
    __syncthreads();
    float acc = ob[c];
    for (int k = 0; k < 128; ++k) acc += xm[k] * oW[k * 128 + c];
    out[c] = acc > 0.f ? acc : 0.f;
}

extern "C" void kernel_launch(void* const* d_in, const int* in_sizes, int n_in,
                              void* d_out, int out_size, void* d_ws, size_t ws_size,
                              hipStream_t stream) {
    const float* x0  = (const float*)d_in[0];
    const int*   ei  = (const int*)d_in[1];
    const float* pW  = (const float*)d_in[2];
    const float* pb  = (const float*)d_in[3];
    const float* W1  = (const float*)d_in[4];
    const float* as1 = (const float*)d_in[5];
    const float* ad1 = (const float*)d_in[6];
    const float* b1  = (const float*)d_in[7];
    const float* bg  = (const float*)d_in[8];
    const float* bb  = (const float*)d_in[9];
    const float* W2  = (const float*)d_in[10];
    const float* as2 = (const float*)d_in[11];
    const float* ad2 = (const float*)d_in[12];
    const float* b2  = (const float*)d_in[13];
    const float* oW  = (const float*)d_in[14];
    const float* ob  = (const float*)d_in[15];
    float* out = (float*)d_out;

    float* ws = (float*)d_ws;
    unsigned short* h1b = (unsigned short*)ws; ws += 3203072;   // 391*128 rows bf16
    unsigned short* x2b = (unsigned short*)ws; ws += 3200000;
    unsigned short* pWt = (unsigned short*)ws; ws += 8192;
    unsigned short* W1t = (unsigned short*)ws; ws += 8192;
    float* aS1   = ws; ws += 200192;
    float* aD1   = ws; ws += 200192;
    float* aS2   = ws; ws += 200000;
    float* aD2   = ws; ws += 200000;
    float* adL   = ws; ws += 400000;
    float* Wacc  = ws; ws += 200000;
    float* va_s  = ws; ws += 512;
    float* va_d  = ws; ws += 512;
    float* y     = ws; ws += 512;
    int* bcur_d  = (int*)ws; ws += NB;
    int* bcur_s  = (int*)ws; ws += NB;
    int2* oe_d   = (int2*)ws; ws += 2 * NN;
    int2* oe_s   = (int2*)ws; ws += 2 * NN;
    int* csr_src = (int*)ws; ws += NB * CAP;
    int* csr_dst = (int*)ws; ws += NB * CAP;
    int* pr_d    = (int*)ws; ws += NB * CAP;
    int* pr_s    = (int*)ws; ws += NB * CAP;

    const int* srcA = ei;
    const int* dstA = ei + NE;

    dim3 blk(256);

    prep_k<<<7, blk, 0, stream>>>(pW, W1, pWt, W1t, W2, as2, ad2, va_s, va_d,
                                  bcur_d, bcur_s, y);
    part_k<<<PGRID, 512, 0, stream>>>(srcA, dstA, bcur_d, bcur_s, pr_d, pr_s);
    fine_k<<<2 * NB, 512, 0, stream>>>(pr_d, bcur_d, oe_d, csr_src,
                                       pr_s, bcur_s, oe_s, csr_dst);

    fgemm_k<<<NB, blk, 0, stream>>>(x0, pWt, W1t, pb, as1, ad1, h1b, aS1, aD1);

    gather1_k<<<12500, blk, 0, stream>>>(csr_src, oe_d, aS1, aD1, h1b, b1, bg, bb,
                                         va_s, va_d, x2b, aS2, aD2);

    dsum_k<<<12500, blk, 0, stream>>>(csr_src, oe_d, aS2, aD2, adL);
    waccg_k<<<12500, blk, 0, stream>>>(csr_dst, oe_s, aS2, adL, Wacc);
    yacc_k<<<512, 64, 0, stream>>>(Wacc, x2b, y);
    final2_k<<<1, 128, 0, stream>>>(y, W2, b2, oW, ob, out);
}